// Round 6
// baseline (399.390 us; speedup 1.0000x reference)
//
#include <hip/hip_runtime.h>
#include <math.h>

#define B_   16
#define C_   1536
#define N_   1024
#define M_   64
#define L_   128
#define G_   256
#define HID_ 512

typedef __attribute__((ext_vector_type(8))) short short8;
typedef __attribute__((ext_vector_type(4))) float floatx4;

__device__ __forceinline__ unsigned short f2bf_rne(float x) {
    unsigned u = __float_as_uint(x);
    unsigned r = u + 0x7fffu + ((u >> 16) & 1u);
    return (unsigned short)(r >> 16);
}
__device__ __forceinline__ unsigned pack_bf2(float lo, float hi) {
    unsigned a = __float_as_uint(lo) + 0x8000u;
    unsigned b = __float_as_uint(hi) + 0x8000u;
    return (a >> 16) | (b & 0xffff0000u);
}
__device__ __forceinline__ float bf2f(unsigned short u) {
    return __uint_as_float(((unsigned)u) << 16);
}
__device__ __forceinline__ void gl2lds16(const void* g, void* l) {
    __builtin_amdgcn_global_load_lds(
        (const __attribute__((address_space(1))) void*)g,
        (__attribute__((address_space(3))) void*)l, 16, 0, 0);
}

// ---------------------------------------------------------------------------
// Weight cast + zero-init of accumulators (agg, draw, rowsum live OUTSIDE the
// xT region so later kernels can't clobber them).
// ---------------------------------------------------------------------------
__global__ __launch_bounds__(256) void cast_w_kernel(
    const float* __restrict__ Wc1, const float* __restrict__ Ws1,
    const float* __restrict__ Wc2, const float* __restrict__ Ws2,
    unsigned short* __restrict__ Wbf, unsigned short* __restrict__ W2,
    float* __restrict__ agg, float* __restrict__ draw,
    float* __restrict__ rowsum)
{
    const int T1 = 1024 * 1536;          // Wbf elems
    const int T2 = 192 * 1024;           // W2 elems
    int idx = blockIdx.x * 256 + threadIdx.x;
    if (idx < T1) {
        float v = (idx < 512 * 1536) ? Wc1[idx] : Ws1[idx - 512 * 1536];
        Wbf[idx] = f2bf_rne(v);
    } else if (idx < T1 + T2) {
        int i2 = idx - T1;
        int row = i2 >> 10, k = i2 & 1023;
        float v = 0.f;
        if (row < 128) { if (k < 512) v = Wc2[row * 512 + k]; }
        else           { if (k >= 512) v = Ws2[(row - 128) * 512 + (k - 512)]; }
        W2[i2] = f2bf_rne(v);
    } else {
        int zi = idx - (T1 + T2);
        if (zi < 131072) agg[zi] = 0.f;
        else if (zi < 131072 + 16384) draw[zi - 131072] = 0.f;
        else if (zi < 131072 + 16384 + 1040) rowsum[zi - 131072 - 16384] = 0.f;
    }
}

// ---------------------------------------------------------------------------
// Transpose+cast: xT[b][n][c] bf16 <- x[b][c][n] fp32.
// ---------------------------------------------------------------------------
__global__ __launch_bounds__(256) void xt_kernel(
    const float* __restrict__ x, unsigned short* __restrict__ xT)
{
    __shared__ float Xs[64][65];
    const int t = threadIdx.x;
    const int n0 = blockIdx.x * 64, c0 = blockIdx.y * 64, b = blockIdx.z;
    const float* xb = x + (long)b * C_ * N_;
    #pragma unroll
    for (int it = 0; it < 16; ++it) {
        int idx = it * 256 + t, cr = idx >> 6, nc = idx & 63;
        Xs[cr][nc] = xb[(long)(c0 + cr) * N_ + n0 + nc];
    }
    __syncthreads();
    unsigned* xo = (unsigned*)(xT + (long)b * N_ * C_);
    #pragma unroll
    for (int it = 0; it < 8; ++it) {
        int idx = it * 256 + t, nr = idx >> 5, pc = idx & 31;
        xo[(long)(n0 + nr) * 768 + (c0 >> 1) + pc] =
            pack_bf2(Xs[2 * pc][nr], Xs[2 * pc + 1][nr]);
    }
}

// ---------------------------------------------------------------------------
// GEMM1 (bf16 MFMA): hT[b][n][o] = relu(W[o] . xT[b][n] + bias). Epilogue
// round-trips C through LDS for 256B-contiguous uint4 global stores.
// ---------------------------------------------------------------------------
__global__ __launch_bounds__(256, 2) void gemm1_kernel(
    const unsigned short* __restrict__ Wbf, const unsigned short* __restrict__ xT,
    const float* __restrict__ bc1, const float* __restrict__ bs1,
    unsigned short* __restrict__ hT)
{
    __shared__ unsigned short sh[8704];        // 17,408 B: As|Bs, reused as Cs
    unsigned short* As = sh;                   // 4096 ushorts (8 KB)
    unsigned short* Bs = sh + 4096;
    const int t = threadIdx.x;
    const int lane = t & 63, w = t >> 6;
    const int n0 = blockIdx.x * 128, o0 = blockIdx.y * 128, b = blockIdx.z;
    const unsigned short* xb = xT + (long)b * N_ * C_;

    const int wo = (w >> 1) * 64, wn = (w & 1) * 64;
    const int lrow = lane & 15, kgrp = lane >> 4;
    const int arow = t >> 2, acol = (t & 3) * 8;

    floatx4 acc[4][4];
    #pragma unroll
    for (int i = 0; i < 4; ++i)
        #pragma unroll
        for (int j = 0; j < 4; ++j) acc[i][j] = (floatx4)0.0f;

    for (int k0 = 0; k0 < C_; k0 += 32) {
        #pragma unroll
        for (int r = 0; r < 2; ++r)
            gl2lds16(Wbf + (long)(o0 + r * 64 + arow) * C_ + k0 + acol,
                     (char*)As + r * 4096 + t * 16);
        #pragma unroll
        for (int r = 0; r < 2; ++r)
            gl2lds16(xb + (long)(n0 + r * 64 + arow) * C_ + k0 + acol,
                     (char*)Bs + r * 4096 + t * 16);
        __syncthreads();
        short8 af[4], bfr[4];
        #pragma unroll
        for (int i = 0; i < 4; ++i)
            af[i] = *(const short8*)((const char*)As +
                        (wo + i * 16 + lrow) * 64 + kgrp * 16);
        #pragma unroll
        for (int j = 0; j < 4; ++j)
            bfr[j] = *(const short8*)((const char*)Bs +
                        (wn + j * 16 + lrow) * 64 + kgrp * 16);
        #pragma unroll
        for (int i = 0; i < 4; ++i)
            #pragma unroll
            for (int j = 0; j < 4; ++j)
                acc[i][j] = __builtin_amdgcn_mfma_f32_16x16x32_bf16(
                    af[i], bfr[j], acc[i][j], 0, 0, 0);
        __syncthreads();
    }

    // epilogue: bias+relu+pack into LDS (stride 272 B), coalesced store
    const float* bias = (o0 < 512) ? bc1 : bs1;
    const int ob = (o0 < 512) ? o0 : o0 - 512;
    for (int half = 0; half < 2; ++half) {
        if ((w & 1) == half) {
            #pragma unroll
            for (int i = 0; i < 4; ++i) {
                int o_loc = wo + i * 16 + kgrp * 4;
                float b0 = bias[ob + o_loc + 0], b1 = bias[ob + o_loc + 1];
                float b2 = bias[ob + o_loc + 2], b3 = bias[ob + o_loc + 3];
                #pragma unroll
                for (int j = 0; j < 4; ++j) {
                    int n_loc = j * 16 + lrow;
                    float v0 = fmaxf(acc[i][j][0] + b0, 0.f);
                    float v1 = fmaxf(acc[i][j][1] + b1, 0.f);
                    float v2 = fmaxf(acc[i][j][2] + b2, 0.f);
                    float v3 = fmaxf(acc[i][j][3] + b3, 0.f);
                    uint2 pk;
                    pk.x = pack_bf2(v0, v1) & 0u;  // placeholder avoid warn
                    pk.x = ((unsigned)f2bf_rne(v0)) | (((unsigned)f2bf_rne(v1)) << 16);
                    pk.y = ((unsigned)f2bf_rne(v2)) | (((unsigned)f2bf_rne(v3)) << 16);
                    *(uint2*)((char*)sh + n_loc * 272 + o_loc * 2) = pk;
                }
            }
        }
        __syncthreads();
        #pragma unroll
        for (int ps = 0; ps < 4; ++ps) {
            int n_loc = ps * 16 + (t >> 4);
            int o8 = (t & 15) * 8;
            uint4 q = *(const uint4*)((const char*)sh + n_loc * 272 + o8 * 2);
            *(uint4*)&hT[((long)b * N_ + n0 + half * 64 + n_loc) * 1024 + o0 + o8] = q;
        }
        __syncthreads();
    }
}

// ---------------------------------------------------------------------------
// GEMM23: rows 0-127 -> fbf (bf16), rows 128-191 -> K = exp(p+bias) fp32,
// with fused Sinkhorn row-sum accumulation (atomics into rowsum[b][m]).
// ---------------------------------------------------------------------------
__global__ __launch_bounds__(256, 2) void gemm23_kernel(
    const unsigned short* __restrict__ W2, const unsigned short* __restrict__ hT,
    const float* __restrict__ bc2, const float* __restrict__ bs2,
    unsigned short* __restrict__ fbf, float* __restrict__ K,
    float* __restrict__ rowsum)
{
    __shared__ unsigned short As[64 * 32];
    __shared__ unsigned short Bs[128 * 32];
    const int t = threadIdx.x;
    const int lane = t & 63, w = t >> 6;
    const int n0 = blockIdx.x * 128, o0 = blockIdx.y * 64, b = blockIdx.z;
    const unsigned short* hTb = hT + (long)b * N_ * 1024;

    const int wo = (w >> 1) * 32, wn = (w & 1) * 64;
    const int lrow = lane & 15, kgrp = lane >> 4;
    const int arow = t >> 2, acol = (t & 3) * 8;

    floatx4 acc[2][4];
    #pragma unroll
    for (int i = 0; i < 2; ++i)
        #pragma unroll
        for (int j = 0; j < 4; ++j) acc[i][j] = (floatx4)0.0f;

    for (int k0 = 0; k0 < 1024; k0 += 32) {
        gl2lds16(W2 + (long)(o0 + arow) * 1024 + k0 + acol, (char*)As + t * 16);
        #pragma unroll
        for (int r = 0; r < 2; ++r)
            gl2lds16(hTb + (long)(n0 + r * 64 + arow) * 1024 + k0 + acol,
                     (char*)Bs + r * 4096 + t * 16);
        __syncthreads();
        short8 af[2], bfr[4];
        #pragma unroll
        for (int i = 0; i < 2; ++i)
            af[i] = *(const short8*)((const char*)As +
                        (wo + i * 16 + lrow) * 64 + kgrp * 16);
        #pragma unroll
        for (int j = 0; j < 4; ++j)
            bfr[j] = *(const short8*)((const char*)Bs +
                        (wn + j * 16 + lrow) * 64 + kgrp * 16);
        #pragma unroll
        for (int i = 0; i < 2; ++i)
            #pragma unroll
            for (int j = 0; j < 4; ++j)
                acc[i][j] = __builtin_amdgcn_mfma_f32_16x16x32_bf16(
                    af[i], bfr[j], acc[i][j], 0, 0, 0);
        __syncthreads();
    }

    if (o0 < 128) {
        // f rows -> bf16
        #pragma unroll
        for (int i = 0; i < 2; ++i) {
            int o = o0 + wo + i * 16 + kgrp * 4;
            #pragma unroll
            for (int j = 0; j < 4; ++j) {
                int n = n0 + wn + j * 16 + lrow;
                #pragma unroll
                for (int r = 0; r < 4; ++r) {
                    int oo = o + r;
                    fbf[((long)b * L_ + oo) * N_ + n] =
                        f2bf_rne(acc[i][j][r] + bc2[oo]);
                }
            }
        }
    } else {
        // p rows -> K = exp(p + bias), plus row-sum partials
        float sloc[2][4] = {};
        #pragma unroll
        for (int i = 0; i < 2; ++i) {
            int m0 = wo + i * 16 + kgrp * 4;
            #pragma unroll
            for (int j = 0; j < 4; ++j) {
                int n = n0 + wn + j * 16 + lrow;
                #pragma unroll
                for (int r = 0; r < 4; ++r) {
                    int m = m0 + r;
                    float val = expf(acc[i][j][r] + bs2[m]);
                    K[((long)b * M_ + m) * N_ + n] = val;
                    sloc[i][r] += val;
                }
            }
        }
        #pragma unroll
        for (int i = 0; i < 2; ++i)
            #pragma unroll
            for (int r = 0; r < 4; ++r) {
                float s = sloc[i][r];
                #pragma unroll
                for (int off = 1; off < 16; off <<= 1) s += __shfl_xor(s, off);
                if (lrow == 0)
                    atomicAdd(&rowsum[b * 65 + wo + i * 16 + kgrp * 4 + r], s);
            }
    }
}

// ---------------------------------------------------------------------------
// Token head GEMVs
// ---------------------------------------------------------------------------
__global__ __launch_bounds__(256) void token1_kernel(
    const float* __restrict__ t_in, const float* __restrict__ Wt1,
    const float* __restrict__ bt1, float* __restrict__ hid)
{
    const int lane = threadIdx.x & 63, w = threadIdx.x >> 6;
    const int o = blockIdx.x * 4 + w, b = blockIdx.y;
    const float4* wr = (const float4*)(Wt1 + (long)o * C_);
    const float4* tb = (const float4*)(t_in + (long)b * C_);
    float acc = 0.f;
    #pragma unroll
    for (int i = 0; i < 6; ++i) {
        float4 a = wr[i * 64 + lane], tv = tb[i * 64 + lane];
        acc += a.x * tv.x + a.y * tv.y + a.z * tv.z + a.w * tv.w;
    }
    #pragma unroll
    for (int off = 1; off < 64; off <<= 1) acc += __shfl_xor(acc, off);
    if (lane == 0) hid[b * HID_ + o] = fmaxf(acc + bt1[o], 0.f);
}

__global__ __launch_bounds__(256) void token2_kernel(
    const float* __restrict__ hid, const float* __restrict__ Wt2,
    const float* __restrict__ bt2, float* __restrict__ tok)
{
    const int lane = threadIdx.x & 63, w = threadIdx.x >> 6;
    const int g = blockIdx.x * 4 + w, b = blockIdx.y;
    const float4* wr = (const float4*)(Wt2 + (long)g * HID_);
    const float4* hb = (const float4*)(hid + (long)b * HID_);
    float acc = 0.f;
    #pragma unroll
    for (int i = 0; i < 2; ++i) {
        float4 a = wr[i * 64 + lane], hv = hb[i * 64 + lane];
        acc += a.x * hv.x + a.y * hv.y + a.z * hv.z + a.w * hv.w;
    }
    #pragma unroll
    for (int off = 1; off < 64; off <<= 1) acc += __shfl_xor(acc, off);
    if (lane == 0) tok[b * G_ + g] = acc + bt2[g];
}

// token3: l2norm of tok; also computes a0 = mu/rowsum (first Sinkhorn u-step)
__global__ __launch_bounds__(256) void token3_kernel(
    const float* __restrict__ tok, float* __restrict__ tokn,
    const float* __restrict__ rowsum, const float* __restrict__ dust,
    float* __restrict__ avec)
{
    __shared__ float red[4];
    const int b = blockIdx.x, t = threadIdx.x;
    float v = tok[b * G_ + t];
    float ss = v * v;
    #pragma unroll
    for (int off = 1; off < 64; off <<= 1) ss += __shfl_xor(ss, off);
    if ((t & 63) == 0) red[t >> 6] = ss;
    if (t < 65) {
        float s  = (t < 64) ? rowsum[b * 65 + t] : 1024.f * expf(dust[0]);
        float mu = (t < 64) ? (1.f / 1088.f) : (1024.f / 1088.f);
        avec[b * 65 + t] = mu / s;
    }
    __syncthreads();
    float inv = 1.f / fmaxf(sqrtf(red[0] + red[1] + red[2] + red[3]), 1e-12f);
    tokn[b * G_ + t] = v * inv;
}

// ---------------------------------------------------------------------------
// Linear-domain Sinkhorn iterations: a = mu/(K b); b = nu/(K^T a).
// ---------------------------------------------------------------------------
__global__ __launch_bounds__(256) void ku_kernel(
    const float* __restrict__ K, const float* __restrict__ dust,
    const float* __restrict__ bvec, float* __restrict__ avec)
{
    const int t = threadIdx.x, lane = t & 63, w = t >> 6;
    const int m = blockIdx.x * 4 + w, b = blockIdx.y;
    if (m > M_) return;
    const float* bv = bvec + b * N_;
    float s = 0.f;
    if (m < M_) {
        const float* row = K + ((long)b * M_ + m) * N_;
        #pragma unroll
        for (int i = 0; i < 16; ++i) {
            int n = i * 64 + lane;
            s += row[n] * bv[n];
        }
    } else {
        #pragma unroll
        for (int i = 0; i < 16; ++i) s += bv[i * 64 + lane];
        s *= expf(dust[0]);
    }
    #pragma unroll
    for (int off = 1; off < 64; off <<= 1) s += __shfl_xor(s, off);
    if (lane == 0) {
        float mu = (m < M_) ? (1.f / 1088.f) : (1024.f / 1088.f);
        avec[b * (M_ + 1) + m] = mu / s;
    }
}

__global__ __launch_bounds__(256) void kv_kernel(
    const float* __restrict__ K, const float* __restrict__ dust,
    const float* __restrict__ avec, float* __restrict__ bvec)
{
    __shared__ float a_s[M_ + 1];
    const int t = threadIdx.x, b = blockIdx.y;
    const int n = blockIdx.x * 256 + t;
    if (t < M_ + 1) a_s[t] = avec[b * (M_ + 1) + t];
    __syncthreads();
    float s = expf(dust[0]) * a_s[M_];
    const float* col = K + (long)b * M_ * N_ + n;
    #pragma unroll
    for (int m = 0; m < M_; ++m) s = fmaf(col[(long)m * N_], a_s[m], s);
    bvec[b * N_ + n] = (1.f / 1088.f) / s;
}

// ---------------------------------------------------------------------------
// tnorm: reads fbf (bf16), computes T, writes fnT[b][n][128] bf16.
// ---------------------------------------------------------------------------
__global__ __launch_bounds__(256) void tnorm_kernel(
    const unsigned short* __restrict__ fbf, const float* __restrict__ Wtp,
    const float* __restrict__ btp, unsigned short* __restrict__ fnT,
    float* __restrict__ T)
{
    __shared__ float Ft[L_][65];
    __shared__ float invs[64];
    __shared__ float wtp_s[L_];
    const int b = blockIdx.y, n0 = blockIdx.x * 64, t = threadIdx.x;

    if (t < L_) wtp_s[t] = Wtp[t];
    #pragma unroll
    for (int it = 0; it < 4; ++it) {
        int l = it * 32 + (t >> 3), c0 = (t & 7) * 8;
        uint4 q = *(const uint4*)(fbf + ((long)(b * L_ + l)) * N_ + n0 + c0);
        Ft[l][c0 + 0] = bf2f((unsigned short)(q.x & 0xffff));
        Ft[l][c0 + 1] = bf2f((unsigned short)(q.x >> 16));
        Ft[l][c0 + 2] = bf2f((unsigned short)(q.y & 0xffff));
        Ft[l][c0 + 3] = bf2f((unsigned short)(q.y >> 16));
        Ft[l][c0 + 4] = bf2f((unsigned short)(q.z & 0xffff));
        Ft[l][c0 + 5] = bf2f((unsigned short)(q.z >> 16));
        Ft[l][c0 + 6] = bf2f((unsigned short)(q.w & 0xffff));
        Ft[l][c0 + 7] = bf2f((unsigned short)(q.w >> 16));
    }
    __syncthreads();
    if (t < 64) {
        float ss = 0.f, dot = 0.f;
        #pragma unroll
        for (int l = 0; l < L_; ++l) {
            float v = Ft[l][t];
            ss = fmaf(v, v, ss);
            dot = fmaf(v, wtp_s[l], dot);
        }
        invs[t] = 1.f / fmaxf(sqrtf(ss), 1e-12f);
        float xx = dot + btp[0];
        T[b * N_ + n0 + t] = (xx > 0.f) ? (xx + log1pf(expf(-xx)))
                                        : log1pf(expf(xx));
    }
    __syncthreads();
    unsigned* fo = (unsigned*)fnT;
    for (int it = 0; it < 16; ++it) {
        int idx = it * 256 + t;
        int nl = idx >> 6, jp = idx & 63;
        float inv = invs[nl];
        fo[(((long)b * N_ + n0 + nl) << 6) + jp] =
            pack_bf2(Ft[2 * jp][nl] * inv, Ft[2 * jp + 1][nl] * inv);
    }
}

// ---------------------------------------------------------------------------
// sim (bf16 MFMA): draw[b][i] += sum_j sigmoid(0.5*(Ti+Tj)*(fn_i.fn_j)+bb)
// ---------------------------------------------------------------------------
__global__ __launch_bounds__(256) void sim_kernel(
    const unsigned short* __restrict__ fnT, const float* __restrict__ T,
    const float* __restrict__ bb, float* __restrict__ draw)
{
    __shared__ unsigned short As[64 * 136];
    __shared__ unsigned short Bs[64 * 136];
    __shared__ float Ti[64], Tj[64];
    const int b = blockIdx.z, i0 = blockIdx.y * 64, j0base = blockIdx.x * 256;
    const int t = threadIdx.x, lane = t & 63, w = t >> 6;
    const int lrow = lane & 15, kgrp = lane >> 4;
    const unsigned short* fb = fnT + (long)b * N_ * 128;
    const float burstb = bb[0];

    if (t < 64) Ti[t] = T[b * N_ + i0 + t];
    const int srow = t >> 4, scol = (t & 15) * 8;
    #pragma unroll
    for (int r = 0; r < 4; ++r) {
        uint4 av = *(const uint4*)(fb + (long)(i0 + r * 16 + srow) * 128 + scol);
        *(uint4*)((char*)As + (r * 16 + srow) * 272 + scol * 2) = av;
    }

    float rs[4] = {0.f, 0.f, 0.f, 0.f};
    for (int jj = 0; jj < 4; ++jj) {
        const int j0 = j0base + jj * 64;
        __syncthreads();
        #pragma unroll
        for (int r = 0; r < 4; ++r) {
            uint4 bv = *(const uint4*)(fb + (long)(j0 + r * 16 + srow) * 128 + scol);
            *(uint4*)((char*)Bs + (r * 16 + srow) * 272 + scol * 2) = bv;
        }
        if (t >= 64 && t < 128) Tj[t - 64] = T[b * N_ + j0 + (t - 64)];
        __syncthreads();

        floatx4 acc[4];
        #pragma unroll
        for (int j = 0; j < 4; ++j) acc[j] = (floatx4)0.0f;
        #pragma unroll
        for (int k0 = 0; k0 < 128; k0 += 32) {
            short8 af = *(const short8*)((const char*)As +
                            (w * 16 + lrow) * 272 + k0 * 2 + kgrp * 16);
            #pragma unroll
            for (int j = 0; j < 4; ++j) {
                short8 bf = *(const short8*)((const char*)Bs +
                                (j * 16 + lrow) * 272 + k0 * 2 + kgrp * 16);
                acc[j] = __builtin_amdgcn_mfma_f32_16x16x32_bf16(af, bf, acc[j], 0, 0, 0);
            }
        }
        #pragma unroll
        for (int j = 0; j < 4; ++j) {
            float Tjv = Tj[j * 16 + lrow];
            #pragma unroll
            for (int r = 0; r < 4; ++r) {
                float Tiv = Ti[w * 16 + kgrp * 4 + r];
                float xarg = 0.5f * (Tiv + Tjv) * acc[j][r] + burstb;
                rs[r] += 1.f / (1.f + expf(-xarg));
            }
        }
    }

    #pragma unroll
    for (int off = 1; off < 16; off <<= 1)
        #pragma unroll
        for (int r = 0; r < 4; ++r) rs[r] += __shfl_xor(rs[r], off);
    if (lrow == 0) {
        #pragma unroll
        for (int r = 0; r < 4; ++r)
            atomicAdd(&draw[b * N_ + i0 + w * 16 + kgrp * 4 + r], rs[r]);
    }
}

// ---------------------------------------------------------------------------
// agg (+ fused wn + final kv): Pch = K*a; s_c = col sum + dust; inline wn;
// cf = wn/s; agg += f . (Pch*cf). f read as bf16.
// ---------------------------------------------------------------------------
__global__ __launch_bounds__(256) void agg_kernel(
    const unsigned short* __restrict__ fbf, const float* __restrict__ K,
    const float* __restrict__ avec, const float* __restrict__ dust,
    const float* __restrict__ draw, const float* __restrict__ bp,
    const float* __restrict__ lamd, float* __restrict__ agg)
{
    __shared__ float fch[L_][65];
    __shared__ float Pch[M_][65];
    __shared__ float a_s[M_ + 1], cf[64];
    const int b = blockIdx.y, n0 = blockIdx.x * 64;
    const int t = threadIdx.x, tx = t & 15, ty = t >> 4;
    const float* Kb = K + (long)b * M_ * N_;

    if (t < M_ + 1) a_s[t] = avec[b * (M_ + 1) + t];

    #pragma unroll
    for (int it = 0; it < 4; ++it) {
        int l = it * 32 + (t >> 3), c0 = (t & 7) * 8;
        uint4 q = *(const uint4*)(fbf + ((long)(b * L_ + l)) * N_ + n0 + c0);
        fch[l][c0 + 0] = bf2f((unsigned short)(q.x & 0xffff));
        fch[l][c0 + 1] = bf2f((unsigned short)(q.x >> 16));
        fch[l][c0 + 2] = bf2f((unsigned short)(q.y & 0xffff));
        fch[l][c0 + 3] = bf2f((unsigned short)(q.y >> 16));
        fch[l][c0 + 4] = bf2f((unsigned short)(q.z & 0xffff));
        fch[l][c0 + 5] = bf2f((unsigned short)(q.z >> 16));
        fch[l][c0 + 6] = bf2f((unsigned short)(q.w & 0xffff));
        fch[l][c0 + 7] = bf2f((unsigned short)(q.w >> 16));
    }
    __syncthreads();
    for (int idx = t; idx < M_ * 64; idx += 256) {
        int m = idx >> 6, c = idx & 63;
        Pch[m][c] = Kb[(long)m * N_ + n0 + c] * a_s[m];
    }
    __syncthreads();

    if (t < 64) {
        float s = expf(dust[0]) * a_s[M_];
        #pragma unroll
        for (int m = 0; m < M_; ++m) s += Pch[m][t];
        float d = powf(draw[b * N_ + n0 + t], bp[0]);
        d = fminf(fmaxf(d, 1e-3f), 1e3f);
        float lam = 1.f / (1.f + expf(-lamd[0]));
        float wnv = (1.f - lam) + lam / (d + 1e-6f);
        cf[t] = wnv / s;
    }
    __syncthreads();

    float acc[8][4] = {};
    for (int n = 0; n < 64; ++n) {
        float cfn = cf[n];
        float fv[8], pv[4];
        #pragma unroll
        for (int i = 0; i < 8; ++i) fv[i] = fch[ty + 16 * i][n];
        #pragma unroll
        for (int j = 0; j < 4; ++j) pv[j] = Pch[tx * 4 + j][n] * cfn;
        #pragma unroll
        for (int i = 0; i < 8; ++i)
            #pragma unroll
            for (int j = 0; j < 4; ++j)
                acc[i][j] = fmaf(fv[i], pv[j], acc[i][j]);
    }
    #pragma unroll
    for (int i = 0; i < 8; ++i)
        #pragma unroll
        for (int j = 0; j < 4; ++j)
            atomicAdd(&agg[((long)b * L_ + (ty + 16 * i)) * M_ + tx * 4 + j],
                      acc[i][j]);
}

// ---------------------------------------------------------------------------
// final: per-cluster l2norm, concat [tok_n, agg_n], global l2norm.
// ---------------------------------------------------------------------------
__global__ __launch_bounds__(256) void final_kernel(
    const float* __restrict__ tokn, const float* __restrict__ agg,
    float* __restrict__ out)
{
    __shared__ float invm[M_];
    __shared__ float red[4];
    __shared__ float s_invtot;
    const int b = blockIdx.x, t = threadIdx.x;
    const float* ab = agg + (long)b * L_ * M_;

    if (t < 64) {
        float ss = 0.f;
        for (int l = 0; l < L_; ++l) {
            float v = ab[l * M_ + t];
            ss = fmaf(v, v, ss);
        }
        invm[t] = 1.f / fmaxf(sqrtf(ss), 1e-12f);
    }
    __syncthreads();

    float part;
    {
        float tn = tokn[b * G_ + t];
        part = tn * tn;
    }
    for (int idx = t; idx < L_ * M_; idx += 256) {
        float v = ab[idx] * invm[idx & 63];
        part = fmaf(v, v, part);
    }
    for (int off = 32; off; off >>= 1) part += __shfl_down(part, off);
    if ((t & 63) == 0) red[t >> 6] = part;
    __syncthreads();
    if (t == 0)
        s_invtot = 1.f / fmaxf(sqrtf(red[0] + red[1] + red[2] + red[3]), 1e-12f);
    __syncthreads();

    const float invtot = s_invtot;
    float* ob = out + (long)b * (G_ + L_ * M_);
    ob[t] = tokn[b * G_ + t] * invtot;
    for (int idx = t; idx < L_ * M_; idx += 256)
        ob[G_ + idx] = ab[idx] * invm[idx & 63] * invtot;
}

// ---------------------------------------------------------------------------
extern "C" void kernel_launch(void* const* d_in, const int* in_sizes, int n_in,
                              void* d_out, int out_size, void* d_ws, size_t ws_size,
                              hipStream_t stream)
{
    const float* x    = (const float*)d_in[0];
    const float* t_in = (const float*)d_in[1];
    const float* Wt1  = (const float*)d_in[2];
    const float* bt1  = (const float*)d_in[3];
    const float* Wt2  = (const float*)d_in[4];
    const float* bt2  = (const float*)d_in[5];
    const float* Wc1  = (const float*)d_in[6];
    const float* bc1  = (const float*)d_in[7];
    const float* Wc2  = (const float*)d_in[8];
    const float* bc2  = (const float*)d_in[9];
    const float* Ws1  = (const float*)d_in[10];
    const float* bs1  = (const float*)d_in[11];
    const float* Ws2  = (const float*)d_in[12];
    const float* bs2  = (const float*)d_in[13];
    const float* Wtp  = (const float*)d_in[14];
    const float* btp  = (const float*)d_in[15];
    const float* dust = (const float*)d_in[16];
    const float* bb   = (const float*)d_in[17];
    const float* bp   = (const float*)d_in[18];
    const float* lamd = (const float*)d_in[19];

    char* wsb = (char*)d_ws;
    // xT (0..50.3M) lives only between xt and gemm1; overlay region after:
    unsigned short* xT  = (unsigned short*)wsb;                 // 50,331,648 B
    unsigned short* fbf = (unsigned short*)(wsb + 0);           //  4,194,304 B
    float* K    = (float*)(wsb + 4194304);                      //  4,194,304 B
    unsigned short* fnT = (unsigned short*)(wsb + 8388608);     //  4,194,304 B
    float* hid  = (float*)(wsb + 12582912);                     //     32,768 B
    float* tok  = (float*)(wsb + 12615680);                     //     16,384 B
    float* tokn = (float*)(wsb + 12632064);                     //     16,384 B
    float* T    = (float*)(wsb + 12648448);                     //     65,536 B
    float* avec = (float*)(wsb + 12713984);                     //      4,160 B
    float* bvec = (float*)(wsb + 12718144);                     //     65,536 B
    unsigned short* hT  = (unsigned short*)(wsb + 50331648);    // 33,554,432 B
    unsigned short* Wbf = (unsigned short*)(wsb + 83886080);    //  3,145,728 B
    unsigned short* W2  = (unsigned short*)(wsb + 87031808);    //    393,216 B
    // zero-initialized early, outside all transient regions:
    float* draw   = (float*)(wsb + 87425024);                   //     65,536 B
    float* agg    = (float*)(wsb + 87490560);                   //    524,288 B
    float* rowsum = (float*)(wsb + 88014848);                   //      4,160 B
    float* out  = (float*)d_out;

    cast_w_kernel<<<7493, 256, 0, stream>>>(Wc1, Ws1, Wc2, Ws2, Wbf, W2,
                                            agg, draw, rowsum);

    xt_kernel    <<<dim3(16, 24, 16), 256, 0, stream>>>(x, xT);
    gemm1_kernel <<<dim3(8, 8, 16), 256, 0, stream>>>(Wbf, xT, bc1, bs1, hT);
    gemm23_kernel<<<dim3(8, 3, 16), 256, 0, stream>>>(W2, hT, bc2, bs2,
                                                      fbf, K, rowsum);

    token1_kernel<<<dim3(128, 16), 256, 0, stream>>>(t_in, Wt1, bt1, hid);
    token2_kernel<<<dim3(64, 16), 256, 0, stream>>>(hid, Wt2, bt2, tok);
    token3_kernel<<<16, 256, 0, stream>>>(tok, tokn, rowsum, dust, avec);

    // Sinkhorn: a0 came from rowsum (token3); 2x (v,u); final v fused in agg
    kv_kernel<<<dim3(4, 16), 256, 0, stream>>>(K, dust, avec, bvec);
    ku_kernel<<<dim3(17, 16), 256, 0, stream>>>(K, dust, bvec, avec);
    kv_kernel<<<dim3(4, 16), 256, 0, stream>>>(K, dust, avec, bvec);
    ku_kernel<<<dim3(17, 16), 256, 0, stream>>>(K, dust, bvec, avec);

    tnorm_kernel<<<dim3(16, 16), 256, 0, stream>>>(fbf, Wtp, btp, fnT, T);
    sim_kernel  <<<dim3(4, 16, 16), 256, 0, stream>>>(fnT, T, bb, draw);
    agg_kernel  <<<dim3(16, 16), 256, 0, stream>>>(fbf, K, avec, dust,
                                                   draw, bp, lamd, agg);
    final_kernel<<<16, 256, 0, stream>>>(tokn, agg, out);
}